// Round 5
// baseline (319.497 us; speedup 1.0000x reference)
//
#include <hip/hip_runtime.h>
#include <hip/hip_bf16.h>
#include <stdint.h>

#define B_   8
#define DIM  1024
#define T_   2048
#define H_   16
#define HD   64

typedef __attribute__((ext_vector_type(8))) short bf16x8;
typedef __attribute__((ext_vector_type(4))) float f32x4;

__device__ __forceinline__ unsigned short f2bf(float f) {
    union { float f; unsigned u; } v{f};
    unsigned r = v.u + 0x7fffu + ((v.u >> 16) & 1u);   // RNE
    return (unsigned short)(r >> 16);
}

// async 16B/lane global->LDS; lds dest must be wave-uniform base (HW adds lane*16)
__device__ __forceinline__ void gl_lds16(const unsigned short* g, unsigned short* l) {
    __builtin_amdgcn_global_load_lds(
        (const __attribute__((address_space(1))) void*)(const void*)g,
        (__attribute__((address_space(3))) void*)(void*)l,
        16, 0, 0);
}

// Read one 16B MFMA fragment from a swizzled [rows][64] bf16 LDS tile.
// Physical 16B-block = logical_colgroup ^ (row&7).
__device__ __forceinline__ bf16x8 ld_frag(const unsigned short* smem, int row, int cg) {
    return *reinterpret_cast<const bf16x8*>(smem + row * 64 + (((cg) ^ (row & 7)) << 3));
}

// ---------------------------------------------------------------------------
// Kernel 1: x (B,DIM,T) f32  ->  XT (B,T,DIM) bf16   (transpose + cast)
// ---------------------------------------------------------------------------
__global__ void xpose_cast(const float* __restrict__ x, unsigned short* __restrict__ xt) {
    __shared__ float tile[64][65];
    const int b = blockIdx.z;
    const int d0 = blockIdx.y * 64, t0 = blockIdx.x * 64;
    const int tid = threadIdx.x;
    const int c = tid & 63;
    const int r0 = tid >> 6;

    const float* xp = x + ((size_t)b * DIM + d0) * T_ + t0;
#pragma unroll
    for (int i = 0; i < 16; ++i) {
        int r = r0 + i * 4;
        tile[r][c] = xp[(size_t)r * T_ + c];
    }
    __syncthreads();
    unsigned short* op = xt + ((size_t)b * T_ + t0) * DIM + d0;
#pragma unroll
    for (int i = 0; i < 16; ++i) {
        int r = r0 + i * 4;
        op[(size_t)r * DIM + c] = f2bf(tile[c][r]);
    }
}

// ---------------------------------------------------------------------------
// Kernel 2: cast w_in, w_out, toep_w to bf16
// ---------------------------------------------------------------------------
__global__ void cast_weights(const float* __restrict__ w_in, const float* __restrict__ w_out,
                             const float* __restrict__ tw,
                             unsigned short* __restrict__ w_in_b, unsigned short* __restrict__ w_out_b,
                             unsigned short* __restrict__ tw_b) {
    int i = blockIdx.x * 256 + threadIdx.x;
    if (i < DIM * DIM) {
        w_in_b[i]  = f2bf(w_in[i]);
        w_out_b[i] = f2bf(w_out[i]);
    }
    if (i < H_ * T_) tw_b[i] = f2bf(tw[i]);
}

// ---------------------------------------------------------------------------
// Kernel 3: build diagonal M-tiles in MFMA *fragment* layout:
// Mf[h][dg][cg][row][j] = w[h][ 64*(dg-1) + row - (cg*8+j) ]  (0 if lag<0)
// ---------------------------------------------------------------------------
__global__ void gen_mfrag(const unsigned short* __restrict__ twb, unsigned short* __restrict__ Mf) {
    const int h = blockIdx.y, dg = blockIdx.x;
    const int D = (dg - 1) * 64;
    unsigned short* out = Mf + (((size_t)h * 32 + dg) << 13);   // 8192 elems per (h,dg)
    for (int v = threadIdx.x; v < 1024; v += 256) {
        int cg = v >> 7, row = v & 127;
        bf16x8 w;
#pragma unroll
        for (int j = 0; j < 8; ++j) {
            int lag = D + row - (cg * 8 + j);
            w[j] = (lag >= 0) ? (short)twb[h * T_ + lag] : (short)0;
        }
        *reinterpret_cast<bf16x8*>(out + (size_t)v * 8) = w;
    }
}

// ---------------------------------------------------------------------------
// GEMM: Out_b(1024 x 2048) = W(1024x1024) @ B_b + bias. 128x128 tile, BK=64,
// 4 waves. Double-buffered LDS + counted vmcnt (T3/T4): stage(i+2) issued
// after the reads-done barrier; vmcnt(8) keeps stage(i+1) in flight.
// ---------------------------------------------------------------------------
template <bool OUT_BF16>
__global__ void gemm_k(const unsigned short* __restrict__ Aw,   // (DIM,DIM) bf16
                       const unsigned short* __restrict__ Bm,   // (B,T,DIM) bf16
                       const float* __restrict__ bias,          // (DIM) f32
                       void* __restrict__ Out) {
    __shared__ __align__(16) unsigned short As[2][128 * 64];
    __shared__ __align__(16) unsigned short Bs[2][128 * 64];

    const int flat = blockIdx.x;                 // 1024 blocks
    const int wid  = (flat & 7) * 128 + (flat >> 3);
    const int nx   = wid & 15;
    const int my   = (wid >> 4) & 7;
    const int b    = wid >> 7;

    const int tid = threadIdx.x, lane = tid & 63, wv = tid >> 6;
    const int m0 = my * 128;
    const int n0 = nx * 128;
    const unsigned short* Bb = Bm + (size_t)b * T_ * DIM;

    const int wr = wv >> 1, wc = wv & 1;
    const int lrow = lane & 15, lg = lane >> 4;
    const int rsub = lane >> 3;
    const int g = (lane & 7) ^ rsub;

    f32x4 acc[4][4] = {};

    auto STAGE = [&](int kt, int p) {
        const int k0 = kt * 64;
#pragma unroll
        for (int it = 0; it < 4; ++it) {
            int ch = wv * 4 + it;
            int r  = ch * 8 + rsub;
            gl_lds16(Aw + (size_t)(m0 + r) * DIM + k0 + g * 8, &As[p][0] + ch * 512);
            gl_lds16(Bb + (size_t)(n0 + r) * DIM + k0 + g * 8, &Bs[p][0] + ch * 512);
        }
    };

    STAGE(0, 0);
    STAGE(1, 1);

    const int NT = DIM / 64;     // 16
    for (int i = 0; i < NT; ++i) {
        const int cur = i & 1;
        if (i + 1 < NT) asm volatile("s_waitcnt vmcnt(8)" ::: "memory");
        else            asm volatile("s_waitcnt vmcnt(0)" ::: "memory");
        __builtin_amdgcn_s_barrier();            // buf cur ready for all waves
        __builtin_amdgcn_sched_barrier(0);

        const unsigned short* Ab = &As[cur][0];
        const unsigned short* Bf = &Bs[cur][0];
        bf16x8 a0[4], b0[4], a1[4], b1[4];
#pragma unroll
        for (int mt = 0; mt < 4; ++mt) a0[mt] = ld_frag(Ab, wr * 64 + mt * 16 + lrow, lg);
#pragma unroll
        for (int nt = 0; nt < 4; ++nt) b0[nt] = ld_frag(Bf, wc * 64 + nt * 16 + lrow, lg);
#pragma unroll
        for (int mt = 0; mt < 4; ++mt) a1[mt] = ld_frag(Ab, wr * 64 + mt * 16 + lrow, 4 + lg);
#pragma unroll
        for (int nt = 0; nt < 4; ++nt) b1[nt] = ld_frag(Bf, wc * 64 + nt * 16 + lrow, 4 + lg);

        asm volatile("s_waitcnt lgkmcnt(0)" ::: "memory");
        __builtin_amdgcn_s_barrier();            // all waves' reads of buf cur done
        __builtin_amdgcn_sched_barrier(0);
        if (i + 2 < NT) STAGE(i + 2, cur);       // WAR-safe overwrite of buf cur

        __builtin_amdgcn_s_setprio(1);
#pragma unroll
        for (int mt = 0; mt < 4; ++mt)
#pragma unroll
            for (int nt = 0; nt < 4; ++nt)
                acc[mt][nt] = __builtin_amdgcn_mfma_f32_16x16x32_bf16(a0[mt], b0[nt], acc[mt][nt], 0, 0, 0);
#pragma unroll
        for (int mt = 0; mt < 4; ++mt)
#pragma unroll
            for (int nt = 0; nt < 4; ++nt)
                acc[mt][nt] = __builtin_amdgcn_mfma_f32_16x16x32_bf16(a1[mt], b1[nt], acc[mt][nt], 0, 0, 0);
        __builtin_amdgcn_s_setprio(0);
    }

    const size_t ob = (size_t)b * DIM * T_;
#pragma unroll
    for (int mt = 0; mt < 4; ++mt) {
        int d = m0 + wr * 64 + mt * 16 + lg * 4;
#pragma unroll
        for (int nt = 0; nt < 4; ++nt) {
            int t = n0 + wc * 64 + nt * 16 + lrow;
#pragma unroll
            for (int r = 0; r < 4; ++r) {
                float v = acc[mt][nt][r] + bias[d + r];
                if constexpr (OUT_BF16)
                    ((unsigned short*)Out)[ob + (size_t)(d + r) * T_ + t] = f2bf(v);
                else
                    ((float*)Out)[ob + (size_t)(d + r) * T_ + t] = v;
            }
        }
    }
}

// ---------------------------------------------------------------------------
// Conv v5: balanced triangular GEMM, A-fragments direct from L2 (no A LDS),
// double-buffered P with counted vmcnt (T3/T4) + setprio (T5).
// wid = bx + 8*b + 64*h ; chunked XCD swizzle -> per-XCD WS L2-resident.
// ---------------------------------------------------------------------------
__global__ void conv5_k(const unsigned short* __restrict__ H1,   // (B,DIM,T) bf16
                        const unsigned short* __restrict__ Mf,   // (H,32,8,128,8) bf16
                        const float* __restrict__ tb,            // (H,T) f32
                        unsigned short* __restrict__ Cb) {       // (B,T,DIM) bf16
    __shared__ __align__(16) unsigned short Ps[2][64 * 64];

    const int flat = blockIdx.x;                 // 1024 blocks
    const int wid  = (flat & 7) * 128 + (flat >> 3);
    const int bx   = wid & 7;
    const int b    = (wid >> 3) & 7;
    const int h    = wid >> 6;

    const int tid = threadIdx.x, lane = tid & 63, wv = tid >> 6;
    const unsigned short* Hb = H1 + ((size_t)b * DIM + h * HD) * T_;
    const unsigned short* Ah = Mf + ((size_t)h * 32) * 8192;

    const int lrow = lane & 15, lg = lane >> 4;
    const int rsub = lane >> 3;
    const int g = (lane & 7) ^ rsub;

    // lane-constant part of the A-fragment offset (elems)
    const int aoff = (lg * 128 + wv * 32 + lrow) * 8;

    auto PSTAGE = [&](int kt, int p) {
        const int t0 = kt * 64;
#pragma unroll
        for (int it = 0; it < 2; ++it) {
            int ch = wv * 2 + it;
            int r  = ch * 8 + rsub;
            gl_lds16(Hb + (size_t)r * T_ + t0 + g * 8, &Ps[p][0] + ch * 512);
        }
    };

#pragma unroll
    for (int ph = 0; ph < 2; ++ph) {
        const int ut = ph ? bx : (T_ / 128 - 1 - bx);
        const int u0 = ut * 128;
        const int nk = 2 * ut + 2;
        f32x4 acc[2][4] = {};

        PSTAGE(0, 0);
        PSTAGE(1, 1);

        for (int kt = 0; kt < nk; ++kt) {
            const int cur = kt & 1;
            if (kt + 1 < nk) asm volatile("s_waitcnt vmcnt(2)" ::: "memory");
            else             asm volatile("s_waitcnt vmcnt(0)" ::: "memory");
            __builtin_amdgcn_s_barrier();
            __builtin_amdgcn_sched_barrier(0);

            const unsigned short* Pb = &Ps[cur][0];
            bf16x8 p0[4], p1[4];
#pragma unroll
            for (int nt = 0; nt < 4; ++nt) p0[nt] = ld_frag(Pb, nt * 16 + lrow, lg);
#pragma unroll
            for (int nt = 0; nt < 4; ++nt) p1[nt] = ld_frag(Pb, nt * 16 + lrow, 4 + lg);

            // A fragments straight from L2 (fragment-layout Mf)
            const int dg = 2 * ut - kt + 1;
            const unsigned short* At = Ah + (size_t)dg * 8192;
            bf16x8 af0[2], af1[2];
#pragma unroll
            for (int mt = 0; mt < 2; ++mt) {
                af0[mt] = *reinterpret_cast<const bf16x8*>(At + aoff + mt * 128);
                af1[mt] = *reinterpret_cast<const bf16x8*>(At + 4096 + aoff + mt * 128);
            }

            asm volatile("s_waitcnt lgkmcnt(0)" ::: "memory");
            __builtin_amdgcn_s_barrier();
            __builtin_amdgcn_sched_barrier(0);
            if (kt + 2 < nk) PSTAGE(kt + 2, cur);

            __builtin_amdgcn_s_setprio(1);
#pragma unroll
            for (int mt = 0; mt < 2; ++mt)
#pragma unroll
                for (int nt = 0; nt < 4; ++nt)
                    acc[mt][nt] = __builtin_amdgcn_mfma_f32_16x16x32_bf16(af0[mt], p0[nt], acc[mt][nt], 0, 0, 0);
#pragma unroll
            for (int mt = 0; mt < 2; ++mt)
#pragma unroll
                for (int nt = 0; nt < 4; ++nt)
                    acc[mt][nt] = __builtin_amdgcn_mfma_f32_16x16x32_bf16(af1[mt], p1[nt], acc[mt][nt], 0, 0, 0);
            __builtin_amdgcn_s_setprio(0);
        }

        // epilogue -> C (B,T,DIM)
        const size_t base = (size_t)b * T_ * DIM + (size_t)h * HD;
#pragma unroll
        for (int mt = 0; mt < 2; ++mt) {
            int u = u0 + wv * 32 + mt * 16 + lg * 4;
            const float* tbp = tb + h * T_ + u;
            float t0v = tbp[0], t1v = tbp[1], t2v = tbp[2], t3v = tbp[3];
#pragma unroll
            for (int nt = 0; nt < 4; ++nt) {
                int d = nt * 16 + lrow;
                size_t p = base + (size_t)u * DIM + d;
                Cb[p]           = f2bf(acc[mt][nt][0] + t0v);
                Cb[p + DIM]     = f2bf(acc[mt][nt][1] + t1v);
                Cb[p + 2 * DIM] = f2bf(acc[mt][nt][2] + t2v);
                Cb[p + 3 * DIM] = f2bf(acc[mt][nt][3] + t3v);
            }
        }
    }
}

// ---------------------------------------------------------------------------
extern "C" void kernel_launch(void* const* d_in, const int* in_sizes, int n_in,
                              void* d_out, int out_size, void* d_ws, size_t ws_size,
                              hipStream_t stream) {
    (void)in_sizes; (void)n_in; (void)out_size; (void)ws_size;
    const float* x      = (const float*)d_in[0];
    const float* w_in   = (const float*)d_in[1];
    const float* b_in   = (const float*)d_in[2];
    const float* w_out  = (const float*)d_in[3];
    const float* b_out  = (const float*)d_in[4];
    const float* toep_w = (const float*)d_in[5];
    const float* toep_b = (const float*)d_in[6];

    char* ws = (char*)d_ws;
    unsigned short* XT    = (unsigned short*)(ws);                 // 32 MiB (B,T,DIM) bf16
    unsigned short* H1    = (unsigned short*)(ws + 33554432);      // 32 MiB (B,DIM,T) bf16
    unsigned short* Cbuf  = (unsigned short*)(ws + 67108864);      // 32 MiB (B,T,DIM) bf16
    unsigned short* winb  = (unsigned short*)(ws + 100663296);     // 2 MiB
    unsigned short* woutb = (unsigned short*)(ws + 102760448);     // 2 MiB
    unsigned short* twb   = (unsigned short*)(ws + 104857600);     // 64 KiB
    unsigned short* Mfrag = (unsigned short*)(ws + 104923136);     // 8 MiB (H,32,8,128,8)

    xpose_cast<<<dim3(T_ / 64, DIM / 64, B_), dim3(256), 0, stream>>>(x, XT);
    cast_weights<<<dim3((DIM * DIM) / 256), dim3(256), 0, stream>>>(w_in, w_out, toep_w, winb, woutb, twb);
    gen_mfrag<<<dim3(32, H_), dim3(256), 0, stream>>>(twb, Mfrag);
    gemm_k<true><<<dim3(1024), dim3(256), 0, stream>>>(winb, XT, b_in, (void*)H1);
    conv5_k<<<dim3(1024), dim3(256), 0, stream>>>(H1, Mfrag, toep_b, Cbuf);
    gemm_k<false><<<dim3(1024), dim3(256), 0, stream>>>(woutb, Cbuf, b_out, d_out);
}

// Round 6
// 155.108 us; speedup vs baseline: 2.0598x; 2.0598x over previous
//
#include <hip/hip_runtime.h>
#include <hip/hip_bf16.h>
#include <stdint.h>

#define B_   8
#define DIM  1024
#define T_   2048
#define H_   16
#define HD   64

typedef __attribute__((ext_vector_type(8))) short bf16x8;
typedef __attribute__((ext_vector_type(4))) float f32x4;
typedef __attribute__((ext_vector_type(4))) unsigned short u16x4;

__device__ __forceinline__ unsigned short f2bf(float f) {
    union { float f; unsigned u; } v{f};
    unsigned r = v.u + 0x7fffu + ((v.u >> 16) & 1u);   // RNE
    return (unsigned short)(r >> 16);
}

// async 16B/lane global->LDS; lds dest must be wave-uniform base (HW adds lane*16)
__device__ __forceinline__ void gl_lds16(const unsigned short* g, unsigned short* l) {
    __builtin_amdgcn_global_load_lds(
        (const __attribute__((address_space(1))) void*)(const void*)g,
        (__attribute__((address_space(3))) void*)(void*)l,
        16, 0, 0);
}

// Read one 16B MFMA fragment from a swizzled [rows][64] bf16 LDS tile.
// Physical 16B-block = logical_colgroup ^ (row&7).
__device__ __forceinline__ bf16x8 ld_frag(const unsigned short* smem, int row, int cg) {
    return *reinterpret_cast<const bf16x8*>(smem + row * 64 + (((cg) ^ (row & 7)) << 3));
}

// ---------------------------------------------------------------------------
// Kernel 1: x (B,DIM,T) f32  ->  XT (B,T,DIM) bf16   (transpose + cast)
// Stores vectorized as ushort4 (4 consecutive d per store).
// ---------------------------------------------------------------------------
__global__ void xpose_cast(const float* __restrict__ x, unsigned short* __restrict__ xt) {
    __shared__ float tile[64][65];
    const int b = blockIdx.z;
    const int d0 = blockIdx.y * 64, t0 = blockIdx.x * 64;
    const int tid = threadIdx.x;
    const int c = tid & 63;
    const int r0 = tid >> 6;

    const float* xp = x + ((size_t)b * DIM + d0) * T_ + t0;
#pragma unroll
    for (int i = 0; i < 16; ++i) {
        int r = r0 + i * 4;                       // d offset
        tile[r][c] = xp[(size_t)r * T_ + c];
    }
    __syncthreads();
    unsigned short* op = xt + ((size_t)b * T_ + t0) * DIM + d0;
    const int ci = (tid & 15) * 4;                // d offset (4-wide)
    const int rr = tid >> 4;                      // t offset base 0..15
#pragma unroll
    for (int i = 0; i < 4; ++i) {
        int r = rr + i * 16;                      // t offset
        u16x4 v;
#pragma unroll
        for (int j = 0; j < 4; ++j) v[j] = f2bf(tile[ci + j][r]);
        *reinterpret_cast<u16x4*>(op + (size_t)r * DIM + ci) = v;
    }
}

// ---------------------------------------------------------------------------
// Kernel 2: cast w_in, w_out, toep_w to bf16
// ---------------------------------------------------------------------------
__global__ void cast_weights(const float* __restrict__ w_in, const float* __restrict__ w_out,
                             const float* __restrict__ tw,
                             unsigned short* __restrict__ w_in_b, unsigned short* __restrict__ w_out_b,
                             unsigned short* __restrict__ tw_b) {
    int i = blockIdx.x * 256 + threadIdx.x;
    if (i < DIM * DIM) {
        w_in_b[i]  = f2bf(w_in[i]);
        w_out_b[i] = f2bf(w_out[i]);
    }
    if (i < H_ * T_) tw_b[i] = f2bf(tw[i]);
}

// ---------------------------------------------------------------------------
// Kernel 3: build diagonal M-tiles in MFMA *fragment* layout:
// Mf[h][dg][cg][row][j] = w[h][ 64*(dg-1) + row - (cg*8+j) ]  (0 if lag<0)
// ---------------------------------------------------------------------------
__global__ void gen_mfrag(const unsigned short* __restrict__ twb, unsigned short* __restrict__ Mf) {
    const int h = blockIdx.y, dg = blockIdx.x;
    const int D = (dg - 1) * 64;
    unsigned short* out = Mf + (((size_t)h * 32 + dg) << 13);   // 8192 elems per (h,dg)
    for (int v = threadIdx.x; v < 1024; v += 256) {
        int cg = v >> 7, row = v & 127;
        bf16x8 w;
#pragma unroll
        for (int j = 0; j < 8; ++j) {
            int lag = D + row - (cg * 8 + j);
            w[j] = (lag >= 0) ? (short)twb[h * T_ + lag] : (short)0;
        }
        *reinterpret_cast<bf16x8*>(out + (size_t)v * 8) = w;
    }
}

// ---------------------------------------------------------------------------
// GEMM: Out_b(1024 x 2048) = W(1024x1024) @ B_b + bias. 128x128 tile, BK=64,
// 4 waves. "Minimum 2-phase": double-buffered LDS, STAGE(i+1) issued before
// compute(i), ONE __syncthreads per K-step (compiler manages waitcnts).
// 1-D grid + chunked XCD swizzle (each XCD owns one batch).
// ---------------------------------------------------------------------------
template <bool OUT_BF16>
__global__ void gemm_k(const unsigned short* __restrict__ Aw,   // (DIM,DIM) bf16
                       const unsigned short* __restrict__ Bm,   // (B,T,DIM) bf16
                       const float* __restrict__ bias,          // (DIM) f32
                       void* __restrict__ Out) {
    __shared__ __align__(16) unsigned short As[2][128 * 64];
    __shared__ __align__(16) unsigned short Bs[2][128 * 64];

    const int flat = blockIdx.x;                 // 1024 blocks
    const int wid  = (flat & 7) * 128 + (flat >> 3);
    const int nx   = wid & 15;
    const int my   = (wid >> 4) & 7;
    const int b    = wid >> 7;

    const int tid = threadIdx.x, lane = tid & 63, wv = tid >> 6;
    const int m0 = my * 128;
    const int n0 = nx * 128;
    const unsigned short* Bb = Bm + (size_t)b * T_ * DIM;

    const int wr = wv >> 1, wc = wv & 1;
    const int lrow = lane & 15, lg = lane >> 4;
    const int rsub = lane >> 3;
    const int g = (lane & 7) ^ rsub;

    f32x4 acc[4][4] = {};

    auto STAGE = [&](int kt, int p) {
        const int k0 = kt * 64;
#pragma unroll
        for (int it = 0; it < 4; ++it) {
            int ch = wv * 4 + it;
            int r  = ch * 8 + rsub;
            gl_lds16(Aw + (size_t)(m0 + r) * DIM + k0 + g * 8, &As[p][0] + ch * 512);
            gl_lds16(Bb + (size_t)(n0 + r) * DIM + k0 + g * 8, &Bs[p][0] + ch * 512);
        }
    };

    STAGE(0, 0);
    __syncthreads();                             // buf0 ready

    const int NT = DIM / 64;                     // 16
    for (int i = 0; i < NT; ++i) {
        const int cur = i & 1;
        if (i + 1 < NT) STAGE(i + 1, cur ^ 1);   // loads fly during compute(i)

        const unsigned short* Ab = &As[cur][0];
        const unsigned short* Bf = &Bs[cur][0];
#pragma unroll
        for (int kk = 0; kk < 2; ++kk) {
            bf16x8 af[4], bfr[4];
#pragma unroll
            for (int mt = 0; mt < 4; ++mt) af[mt]  = ld_frag(Ab, wr * 64 + mt * 16 + lrow, kk * 4 + lg);
#pragma unroll
            for (int nt = 0; nt < 4; ++nt) bfr[nt] = ld_frag(Bf, wc * 64 + nt * 16 + lrow, kk * 4 + lg);
#pragma unroll
            for (int mt = 0; mt < 4; ++mt)
#pragma unroll
                for (int nt = 0; nt < 4; ++nt)
                    acc[mt][nt] = __builtin_amdgcn_mfma_f32_16x16x32_bf16(af[mt], bfr[nt], acc[mt][nt], 0, 0, 0);
        }
        __syncthreads();                         // stage(i+1) done + reads of buf cur done
    }

    const size_t ob = (size_t)b * DIM * T_;
#pragma unroll
    for (int mt = 0; mt < 4; ++mt) {
        int d = m0 + wr * 64 + mt * 16 + lg * 4;
#pragma unroll
        for (int nt = 0; nt < 4; ++nt) {
            int t = n0 + wc * 64 + nt * 16 + lrow;
#pragma unroll
            for (int r = 0; r < 4; ++r) {
                float v = acc[mt][nt][r] + bias[d + r];
                if constexpr (OUT_BF16)
                    ((unsigned short*)Out)[ob + (size_t)(d + r) * T_ + t] = f2bf(v);
                else
                    ((float*)Out)[ob + (size_t)(d + r) * T_ + t] = v;
            }
        }
    }
}

// ---------------------------------------------------------------------------
// Conv v4 (proven R3 form): balanced triangular GEMM, A-fragments direct from
// L2 (no A LDS), double-buffered P, ONE barrier per K-step, h-major XCD chunk.
// ---------------------------------------------------------------------------
__global__ void conv4_k(const unsigned short* __restrict__ H1,   // (B,DIM,T) bf16
                        const unsigned short* __restrict__ Mf,   // (H,32,8,128,8) bf16
                        const float* __restrict__ tb,            // (H,T) f32
                        unsigned short* __restrict__ Cb) {       // (B,T,DIM) bf16
    __shared__ __align__(16) unsigned short Ps[2][64 * 64];

    const int flat = blockIdx.x;                 // 1024 blocks
    const int wid  = (flat & 7) * 128 + (flat >> 3);
    const int bx   = wid & 7;
    const int b    = (wid >> 3) & 7;
    const int h    = wid >> 6;

    const int tid = threadIdx.x, lane = tid & 63, wv = tid >> 6;
    const unsigned short* Hb = H1 + ((size_t)b * DIM + h * HD) * T_;
    const unsigned short* Ah = Mf + ((size_t)h * 32) * 8192;

    const int lrow = lane & 15, lg = lane >> 4;
    const int rsub = lane >> 3;
    const int g = (lane & 7) ^ rsub;

    // lane-constant part of the A-fragment offset (elems)
    const int aoff = (lg * 128 + wv * 32 + lrow) * 8;

#pragma unroll
    for (int ph = 0; ph < 2; ++ph) {
        const int ut = ph ? bx : (T_ / 128 - 1 - bx);
        const int u0 = ut * 128;
        const int nk = 2 * ut + 2;
        f32x4 acc[2][4] = {};

        // prologue: stage P(kt=0) into buf 0
#pragma unroll
        for (int it = 0; it < 2; ++it) {
            int ch = wv * 2 + it;
            int r  = ch * 8 + rsub;
            gl_lds16(Hb + (size_t)r * T_ + g * 8, &Ps[0][0] + ch * 512);
        }
        __syncthreads();

        for (int kt = 0; kt < nk; ++kt) {
            const int cur = kt & 1;
            // stage next P tile into the other buffer (issued before compute)
            if (kt + 1 < nk) {
                const int t0n = (kt + 1) * 64;
#pragma unroll
                for (int it = 0; it < 2; ++it) {
                    int ch = wv * 2 + it;
                    int r  = ch * 8 + rsub;
                    gl_lds16(Hb + (size_t)r * T_ + t0n + g * 8, &Ps[cur ^ 1][0] + ch * 512);
                }
            }
            // A fragments straight from L2 (fragment-layout Mf)
            const int dg = 2 * ut - kt + 1;
            const unsigned short* At = Ah + (size_t)dg * 8192;
            bf16x8 af0[2], af1[2];
#pragma unroll
            for (int mt = 0; mt < 2; ++mt) {
                af0[mt] = *reinterpret_cast<const bf16x8*>(At + aoff + mt * 128);
                af1[mt] = *reinterpret_cast<const bf16x8*>(At + 4096 + aoff + mt * 128);
            }
            const unsigned short* Pb = &Ps[cur][0];
            bf16x8 bfr[4];
#pragma unroll
            for (int nt = 0; nt < 4; ++nt) bfr[nt] = ld_frag(Pb, nt * 16 + lrow, lg);
#pragma unroll
            for (int mt = 0; mt < 2; ++mt)
#pragma unroll
                for (int nt = 0; nt < 4; ++nt)
                    acc[mt][nt] = __builtin_amdgcn_mfma_f32_16x16x32_bf16(af0[mt], bfr[nt], acc[mt][nt], 0, 0, 0);
#pragma unroll
            for (int nt = 0; nt < 4; ++nt) bfr[nt] = ld_frag(Pb, nt * 16 + lrow, 4 + lg);
#pragma unroll
            for (int mt = 0; mt < 2; ++mt)
#pragma unroll
                for (int nt = 0; nt < 4; ++nt)
                    acc[mt][nt] = __builtin_amdgcn_mfma_f32_16x16x32_bf16(af1[mt], bfr[nt], acc[mt][nt], 0, 0, 0);

            __syncthreads();   // drains staging loads, then barrier
        }

        // epilogue -> C (B,T,DIM)
        const size_t base = (size_t)b * T_ * DIM + (size_t)h * HD;
#pragma unroll
        for (int mt = 0; mt < 2; ++mt) {
            int u = u0 + wv * 32 + mt * 16 + lg * 4;
            const float* tbp = tb + h * T_ + u;
            float t0v = tbp[0], t1v = tbp[1], t2v = tbp[2], t3v = tbp[3];
#pragma unroll
            for (int nt = 0; nt < 4; ++nt) {
                int d = nt * 16 + lrow;
                size_t p = base + (size_t)u * DIM + d;
                Cb[p]           = f2bf(acc[mt][nt][0] + t0v);
                Cb[p + DIM]     = f2bf(acc[mt][nt][1] + t1v);
                Cb[p + 2 * DIM] = f2bf(acc[mt][nt][2] + t2v);
                Cb[p + 3 * DIM] = f2bf(acc[mt][nt][3] + t3v);
            }
        }
    }
}

// ---------------------------------------------------------------------------
extern "C" void kernel_launch(void* const* d_in, const int* in_sizes, int n_in,
                              void* d_out, int out_size, void* d_ws, size_t ws_size,
                              hipStream_t stream) {
    (void)in_sizes; (void)n_in; (void)out_size; (void)ws_size;
    const float* x      = (const float*)d_in[0];
    const float* w_in   = (const float*)d_in[1];
    const float* b_in   = (const float*)d_in[2];
    const float* w_out  = (const float*)d_in[3];
    const float* b_out  = (const float*)d_in[4];
    const float* toep_w = (const float*)d_in[5];
    const float* toep_b = (const float*)d_in[6];

    char* ws = (char*)d_ws;
    unsigned short* XT    = (unsigned short*)(ws);                 // 32 MiB (B,T,DIM) bf16
    unsigned short* H1    = (unsigned short*)(ws + 33554432);      // 32 MiB (B,DIM,T) bf16
    unsigned short* Cbuf  = (unsigned short*)(ws + 67108864);      // 32 MiB (B,T,DIM) bf16
    unsigned short* winb  = (unsigned short*)(ws + 100663296);     // 2 MiB
    unsigned short* woutb = (unsigned short*)(ws + 102760448);     // 2 MiB
    unsigned short* twb   = (unsigned short*)(ws + 104857600);     // 64 KiB
    unsigned short* Mfrag = (unsigned short*)(ws + 104923136);     // 8 MiB (H,32,8,128,8)

    xpose_cast<<<dim3(T_ / 64, DIM / 64, B_), dim3(256), 0, stream>>>(x, XT);
    cast_weights<<<dim3((DIM * DIM) / 256), dim3(256), 0, stream>>>(w_in, w_out, toep_w, winb, woutb, twb);
    gen_mfrag<<<dim3(32, H_), dim3(256), 0, stream>>>(twb, Mfrag);
    gemm_k<true><<<dim3(1024), dim3(256), 0, stream>>>(winb, XT, b_in, (void*)H1);
    conv4_k<<<dim3(1024), dim3(256), 0, stream>>>(H1, Mfrag, toep_b, Cbuf);
    gemm_k<false><<<dim3(1024), dim3(256), 0, stream>>>(woutb, Cbuf, b_out, d_out);
}

// Round 8
// 151.460 us; speedup vs baseline: 2.1095x; 1.0241x over previous
//
#include <hip/hip_runtime.h>
#include <hip/hip_bf16.h>
#include <stdint.h>

#define B_   8
#define DIM  1024
#define T_   2048
#define H_   16
#define HD   64

typedef __attribute__((ext_vector_type(8))) short bf16x8;
typedef __attribute__((ext_vector_type(4))) float f32x4;
typedef __attribute__((ext_vector_type(4))) unsigned short u16x4;

__device__ __forceinline__ unsigned short f2bf(float f) {
    union { float f; unsigned u; } v{f};
    unsigned r = v.u + 0x7fffu + ((v.u >> 16) & 1u);   // RNE
    return (unsigned short)(r >> 16);
}

// async 16B/lane global->LDS; lds dest must be wave-uniform base (HW adds lane*16)
__device__ __forceinline__ void gl_lds16(const unsigned short* g, unsigned short* l) {
    __builtin_amdgcn_global_load_lds(
        (const __attribute__((address_space(1))) void*)(const void*)g,
        (__attribute__((address_space(3))) void*)(void*)l,
        16, 0, 0);
}

// Read one 16B MFMA fragment from a swizzled [rows][64] bf16 LDS tile.
// Physical 16B-block = logical_colgroup ^ (row&7).
__device__ __forceinline__ bf16x8 ld_frag(const unsigned short* smem, int row, int cg) {
    return *reinterpret_cast<const bf16x8*>(smem + row * 64 + (((cg) ^ (row & 7)) << 3));
}

// ---------------------------------------------------------------------------
// Kernel 1: x (B,DIM,T) f32  ->  XT (B,T,DIM) bf16   (transpose + cast)
// ---------------------------------------------------------------------------
__global__ void xpose_cast(const float* __restrict__ x, unsigned short* __restrict__ xt) {
    __shared__ float tile[64][65];
    const int b = blockIdx.z;
    const int d0 = blockIdx.y * 64, t0 = blockIdx.x * 64;
    const int tid = threadIdx.x;
    const int c = tid & 63;
    const int r0 = tid >> 6;

    const float* xp = x + ((size_t)b * DIM + d0) * T_ + t0;
#pragma unroll
    for (int i = 0; i < 16; ++i) {
        int r = r0 + i * 4;                       // d offset
        tile[r][c] = xp[(size_t)r * T_ + c];
    }
    __syncthreads();
    unsigned short* op = xt + ((size_t)b * T_ + t0) * DIM + d0;
    const int ci = (tid & 15) * 4;                // d offset (4-wide)
    const int rr = tid >> 4;                      // t offset base 0..15
#pragma unroll
    for (int i = 0; i < 4; ++i) {
        int r = rr + i * 16;                      // t offset
        u16x4 v;
#pragma unroll
        for (int j = 0; j < 4; ++j) v[j] = f2bf(tile[ci + j][r]);
        *reinterpret_cast<u16x4*>(op + (size_t)r * DIM + ci) = v;
    }
}

// ---------------------------------------------------------------------------
// Kernel 2: cast w_in, w_out, toep_w to bf16
// ---------------------------------------------------------------------------
__global__ void cast_weights(const float* __restrict__ w_in, const float* __restrict__ w_out,
                             const float* __restrict__ tw,
                             unsigned short* __restrict__ w_in_b, unsigned short* __restrict__ w_out_b,
                             unsigned short* __restrict__ tw_b) {
    int i = blockIdx.x * 256 + threadIdx.x;
    if (i < DIM * DIM) {
        w_in_b[i]  = f2bf(w_in[i]);
        w_out_b[i] = f2bf(w_out[i]);
    }
    if (i < H_ * T_) tw_b[i] = f2bf(tw[i]);
}

// ---------------------------------------------------------------------------
// Kernel 3: build diagonal M-tiles in MFMA *fragment* layout:
// Mf[h][dg][cg][row][j] = w[h][ 64*(dg-1) + row - (cg*8+j) ]  (0 if lag<0)
// ---------------------------------------------------------------------------
__global__ void gen_mfrag(const unsigned short* __restrict__ twb, unsigned short* __restrict__ Mf) {
    const int h = blockIdx.y, dg = blockIdx.x;
    const int D = (dg - 1) * 64;
    unsigned short* out = Mf + (((size_t)h * 32 + dg) << 13);   // 8192 elems per (h,dg)
    for (int v = threadIdx.x; v < 1024; v += 256) {
        int cg = v >> 7, row = v & 127;
        bf16x8 w;
#pragma unroll
        for (int j = 0; j < 8; ++j) {
            int lag = D + row - (cg * 8 + j);
            w[j] = (lag >= 0) ? (short)twb[h * T_ + lag] : (short)0;
        }
        *reinterpret_cast<bf16x8*>(out + (size_t)v * 8) = w;
    }
}

// ---------------------------------------------------------------------------
// Kernel 3b: rearrange a (DIM,DIM) bf16 weight into MFMA fragment layout:
// Wf[my][kt][cg][row][j] = W[my*128+row][kt*64 + cg*8 + j]
//   my in [0,8), kt in [0,16), cg in [0,8), row in [0,128). 2 MiB, L2-hot.
// ---------------------------------------------------------------------------
__global__ void gen_wfrag(const unsigned short* __restrict__ Wb, unsigned short* __restrict__ Wf) {
    const int kt = blockIdx.x, my = blockIdx.y;
    unsigned short* out = Wf + (((size_t)my * 16 + kt) << 13);
    for (int v = threadIdx.x; v < 1024; v += 256) {
        int cg = v >> 7, row = v & 127;
        bf16x8 w = *reinterpret_cast<const bf16x8*>(
            Wb + (size_t)(my * 128 + row) * DIM + kt * 64 + cg * 8);
        *reinterpret_cast<bf16x8*>(out + (size_t)v * 8) = w;
    }
}

// ---------------------------------------------------------------------------
// GEMM v2 (conv4 structure): Out_b = W @ B_b + bias. 128x128 tile, BK=64,
// 4 waves (2x2 of 64x64). A-fragments DIRECT FROM L2 (fragment-layout Wf,
// no A LDS); B double-buffered in LDS, stage(i+1) issued before compute(i),
// ONE __syncthreads per K-step. 1-D grid + chunked XCD swizzle.
// ---------------------------------------------------------------------------
template <bool OUT_BF16>
__global__ void gemm2_k(const unsigned short* __restrict__ Wf,   // (8,16,8,128,8) bf16
                        const unsigned short* __restrict__ Bm,   // (B,T,DIM) bf16
                        const float* __restrict__ bias,          // (DIM) f32
                        void* __restrict__ Out) {
    __shared__ __align__(16) unsigned short Bs[2][128 * 64];

    const int flat = blockIdx.x;                 // 1024 blocks
    const int wid  = (flat & 7) * 128 + (flat >> 3);
    const int nx   = wid & 15;
    const int my   = (wid >> 4) & 7;
    const int b    = wid >> 7;

    const int tid = threadIdx.x, lane = tid & 63, wv = tid >> 6;
    const int m0 = my * 128;
    const int n0 = nx * 128;
    const unsigned short* Bb = Bm + (size_t)b * T_ * DIM + (size_t)n0 * DIM;
    const unsigned short* Aw = Wf + (((size_t)my * 16) << 13);

    const int wr = wv >> 1, wc = wv & 1;
    const int lrow = lane & 15, lg = lane >> 4;
    const int rsub = lane >> 3;
    const int g = (lane & 7) ^ rsub;

    // lane-constant part of the A-fragment offset (elems): cg=lg, row=wr*64+lrow
    const int aoff = (lg * 128 + wr * 64 + lrow) * 8;

    f32x4 acc[4][4] = {};

    auto BSTAGE = [&](int kt, int p) {
        const int k0 = kt * 64;
#pragma unroll
        for (int it = 0; it < 4; ++it) {
            int ch = wv * 4 + it;                 // 16 chunks of 8 rows
            int r  = ch * 8 + rsub;
            gl_lds16(Bb + (size_t)r * DIM + k0 + g * 8, &Bs[p][0] + ch * 512);
        }
    };

    BSTAGE(0, 0);
    __syncthreads();

    const int NT = DIM / 64;                     // 16
    for (int kt = 0; kt < NT; ++kt) {
        const int cur = kt & 1;
        if (kt + 1 < NT) BSTAGE(kt + 1, cur ^ 1);   // loads fly during compute

        // A fragments straight from L2 (fragment-layout Wf)
        const unsigned short* At = Aw + ((size_t)kt << 13);
        bf16x8 af0[4], af1[4];
#pragma unroll
        for (int mt = 0; mt < 4; ++mt) {
            af0[mt] = *reinterpret_cast<const bf16x8*>(At + aoff + mt * 128);
            af1[mt] = *reinterpret_cast<const bf16x8*>(At + 4096 + aoff + mt * 128);
        }

        const unsigned short* Pb = &Bs[cur][0];
        bf16x8 bfr[4];
#pragma unroll
        for (int nt = 0; nt < 4; ++nt) bfr[nt] = ld_frag(Pb, wc * 64 + nt * 16 + lrow, lg);
#pragma unroll
        for (int mt = 0; mt < 4; ++mt)
#pragma unroll
            for (int nt = 0; nt < 4; ++nt)
                acc[mt][nt] = __builtin_amdgcn_mfma_f32_16x16x32_bf16(af0[mt], bfr[nt], acc[mt][nt], 0, 0, 0);
#pragma unroll
        for (int nt = 0; nt < 4; ++nt) bfr[nt] = ld_frag(Pb, wc * 64 + nt * 16 + lrow, 4 + lg);
#pragma unroll
        for (int mt = 0; mt < 4; ++mt)
#pragma unroll
            for (int nt = 0; nt < 4; ++nt)
                acc[mt][nt] = __builtin_amdgcn_mfma_f32_16x16x32_bf16(af1[mt], bfr[nt], acc[mt][nt], 0, 0, 0);

        __syncthreads();                         // stage done + reads of buf cur done
    }

    const size_t ob = (size_t)b * DIM * T_;
#pragma unroll
    for (int mt = 0; mt < 4; ++mt) {
        int d = m0 + wr * 64 + mt * 16 + lg * 4;
#pragma unroll
        for (int nt = 0; nt < 4; ++nt) {
            int t = n0 + wc * 64 + nt * 16 + lrow;
#pragma unroll
            for (int r = 0; r < 4; ++r) {
                float v = acc[mt][nt][r] + bias[d + r];
                if constexpr (OUT_BF16)
                    ((unsigned short*)Out)[ob + (size_t)(d + r) * T_ + t] = f2bf(v);
                else
                    ((float*)Out)[ob + (size_t)(d + r) * T_ + t] = v;
            }
        }
    }
}

// ---------------------------------------------------------------------------
// Conv v4 (proven R3 form): balanced triangular GEMM, A-fragments direct from
// L2 (no A LDS), double-buffered P, ONE barrier per K-step, h-major XCD chunk.
// ---------------------------------------------------------------------------
__global__ void conv4_k(const unsigned short* __restrict__ H1,   // (B,DIM,T) bf16
                        const unsigned short* __restrict__ Mf,   // (H,32,8,128,8) bf16
                        const float* __restrict__ tb,            // (H,T) f32
                        unsigned short* __restrict__ Cb) {       // (B,T,DIM) bf16
    __shared__ __align__(16) unsigned short Ps[2][64 * 64];

    const int flat = blockIdx.x;                 // 1024 blocks
    const int wid  = (flat & 7) * 128 + (flat >> 3);
    const int bx   = wid & 7;
    const int b    = (wid >> 3) & 7;
    const int h    = wid >> 6;

    const int tid = threadIdx.x, lane = tid & 63, wv = tid >> 6;
    const unsigned short* Hb = H1 + ((size_t)b * DIM + h * HD) * T_;
    const unsigned short* Ah = Mf + ((size_t)h * 32) * 8192;

    const int lrow = lane & 15, lg = lane >> 4;
    const int rsub = lane >> 3;
    const int g = (lane & 7) ^ rsub;

    // lane-constant part of the A-fragment offset (elems)
    const int aoff = (lg * 128 + wv * 32 + lrow) * 8;

#pragma unroll
    for (int ph = 0; ph < 2; ++ph) {
        const int ut = ph ? bx : (T_ / 128 - 1 - bx);
        const int u0 = ut * 128;
        const int nk = 2 * ut + 2;
        f32x4 acc[2][4] = {};

        // prologue: stage P(kt=0) into buf 0
#pragma unroll
        for (int it = 0; it < 2; ++it) {
            int ch = wv * 2 + it;
            int r  = ch * 8 + rsub;
            gl_lds16(Hb + (size_t)r * T_ + g * 8, &Ps[0][0] + ch * 512);
        }
        __syncthreads();

        for (int kt = 0; kt < nk; ++kt) {
            const int cur = kt & 1;
            // stage next P tile into the other buffer (issued before compute)
            if (kt + 1 < nk) {
                const int t0n = (kt + 1) * 64;
#pragma unroll
                for (int it = 0; it < 2; ++it) {
                    int ch = wv * 2 + it;
                    int r  = ch * 8 + rsub;
                    gl_lds16(Hb + (size_t)r * T_ + t0n + g * 8, &Ps[cur ^ 1][0] + ch * 512);
                }
            }
            // A fragments straight from L2 (fragment-layout Mf)
            const int dg = 2 * ut - kt + 1;
            const unsigned short* At = Ah + (size_t)dg * 8192;
            bf16x8 af0[2], af1[2];
#pragma unroll
            for (int mt = 0; mt < 2; ++mt) {
                af0[mt] = *reinterpret_cast<const bf16x8*>(At + aoff + mt * 128);
                af1[mt] = *reinterpret_cast<const bf16x8*>(At + 4096 + aoff + mt * 128);
            }
            const unsigned short* Pb = &Ps[cur][0];
            bf16x8 bfr[4];
#pragma unroll
            for (int nt = 0; nt < 4; ++nt) bfr[nt] = ld_frag(Pb, nt * 16 + lrow, lg);
#pragma unroll
            for (int mt = 0; mt < 2; ++mt)
#pragma unroll
                for (int nt = 0; nt < 4; ++nt)
                    acc[mt][nt] = __builtin_amdgcn_mfma_f32_16x16x32_bf16(af0[mt], bfr[nt], acc[mt][nt], 0, 0, 0);
#pragma unroll
            for (int nt = 0; nt < 4; ++nt) bfr[nt] = ld_frag(Pb, nt * 16 + lrow, 4 + lg);
#pragma unroll
            for (int mt = 0; mt < 2; ++mt)
#pragma unroll
                for (int nt = 0; nt < 4; ++nt)
                    acc[mt][nt] = __builtin_amdgcn_mfma_f32_16x16x32_bf16(af1[mt], bfr[nt], acc[mt][nt], 0, 0, 0);

            __syncthreads();   // drains staging loads, then barrier
        }

        // epilogue -> C (B,T,DIM)
        const size_t base = (size_t)b * T_ * DIM + (size_t)h * HD;
#pragma unroll
        for (int mt = 0; mt < 2; ++mt) {
            int u = u0 + wv * 32 + mt * 16 + lg * 4;
            const float* tbp = tb + h * T_ + u;
            float t0v = tbp[0], t1v = tbp[1], t2v = tbp[2], t3v = tbp[3];
#pragma unroll
            for (int nt = 0; nt < 4; ++nt) {
                int d = nt * 16 + lrow;
                size_t p = base + (size_t)u * DIM + d;
                Cb[p]           = f2bf(acc[mt][nt][0] + t0v);
                Cb[p + DIM]     = f2bf(acc[mt][nt][1] + t1v);
                Cb[p + 2 * DIM] = f2bf(acc[mt][nt][2] + t2v);
                Cb[p + 3 * DIM] = f2bf(acc[mt][nt][3] + t3v);
            }
        }
    }
}

// ---------------------------------------------------------------------------
extern "C" void kernel_launch(void* const* d_in, const int* in_sizes, int n_in,
                              void* d_out, int out_size, void* d_ws, size_t ws_size,
                              hipStream_t stream) {
    (void)in_sizes; (void)n_in; (void)out_size; (void)ws_size;
    const float* x      = (const float*)d_in[0];
    const float* w_in   = (const float*)d_in[1];
    const float* b_in   = (const float*)d_in[2];
    const float* w_out  = (const float*)d_in[3];
    const float* b_out  = (const float*)d_in[4];
    const float* toep_w = (const float*)d_in[5];
    const float* toep_b = (const float*)d_in[6];

    char* ws = (char*)d_ws;
    unsigned short* XT    = (unsigned short*)(ws);                 // 32 MiB (B,T,DIM) bf16
    unsigned short* H1    = (unsigned short*)(ws + 33554432);      // 32 MiB (B,DIM,T) bf16
    unsigned short* Cbuf  = (unsigned short*)(ws + 67108864);      // 32 MiB (B,T,DIM) bf16
    unsigned short* winb  = (unsigned short*)(ws + 100663296);     // 2 MiB
    unsigned short* woutb = (unsigned short*)(ws + 102760448);     // 2 MiB
    unsigned short* twb   = (unsigned short*)(ws + 104857600);     // 64 KiB
    unsigned short* Mfrag = (unsigned short*)(ws + 104923136);     // 8 MiB (H,32,8,128,8)
    unsigned short* WfI   = (unsigned short*)(ws + 113311744);     // 2 MiB (8,16,8,128,8)
    unsigned short* WfO   = (unsigned short*)(ws + 115408896);     // 2 MiB

    xpose_cast<<<dim3(T_ / 64, DIM / 64, B_), dim3(256), 0, stream>>>(x, XT);
    cast_weights<<<dim3((DIM * DIM) / 256), dim3(256), 0, stream>>>(w_in, w_out, toep_w, winb, woutb, twb);
    gen_mfrag<<<dim3(32, H_), dim3(256), 0, stream>>>(twb, Mfrag);
    gen_wfrag<<<dim3(16, 8), dim3(256), 0, stream>>>(winb, WfI);
    gen_wfrag<<<dim3(16, 8), dim3(256), 0, stream>>>(woutb, WfO);
    gemm2_k<true><<<dim3(1024), dim3(256), 0, stream>>>(WfI, XT, b_in, (void*)H1);
    conv4_k<<<dim3(1024), dim3(256), 0, stream>>>(H1, Mfrag, toep_b, Cbuf);
    gemm2_k<false><<<dim3(1024), dim3(256), 0, stream>>>(WfO, Cbuf, b_out, d_out);
}